// Round 23
// baseline (32.214 us; speedup 1.0000x reference)
//
#include <hip/hip_runtime.h>

// RNNFFT: depth-10 radix-2 butterfly network over last dim (1024).
// v = x; for l = 9..0: y = B_l(w_l * v); v = (l==1) ? y : x + y
// Pairs at level l: (e, e^h), h = 512>>l. Twiddle: bw[OFF[l] + (e & (n_l-1))].
// Mix (lw^T): role-j: y = lw[j][j]*t_self + lw[1-j][j]*t_partner.
//
// Structure = r11 two-layout butterfly + r22 nontemporal stores:
//   Layout A (e=lane*16+r): levels 9..6 in-lane; 5,4 via DPP quad_perm.
//   Per-wave LDS transpose (XOR-swizzled). bw staged in LDS.
//   Layout B (e=r*64+lane): levels 3..0 in-lane; nt coalesced B stores.
//   B-layout residual re-read from GLOBAL (not LDS): with nt stores keeping x
//   L3-resident (r22's win), the re-read is an L2/L3 hit, and dropping bufx
//   cuts LDS 40->24KB: 4 -> 6 blocks/CU (+50% latency-hiding waves) - the
//   exact lever the 33%-VALUBusy equilibrium needs.
// Ledger: occupancy-alone null (r4,r19), VALU null (r14), latency null (r15),
// DS-count register-blocked (r18), VMEM null (r20), nt stores +1us (r22).
// Per-element arithmetic identical to r11 (absmax 7.450581e-9).

constexpr int VECLEN = 1024;

__device__ __forceinline__ int swz(int f) {      // XOR bits[4:2] with bits[7:5]
  return f ^ (((f >> 5) & 7) << 2);              // preserves 16B groups
}

template<int L, bool RESL>
__device__ __forceinline__ void level_inlane(float (&v)[16], const float (&xr)[16],
                                             const float* __restrict__ bw,
                                             const float* __restrict__ lw) {
  constexpr int n = VECLEN >> L;          // 16, 8, 4, 2
  constexpr int h = n >> 1;               // 8, 4, 2, 1
  constexpr int off = 2048 - (2048 >> L); // OFFSETS[L]
  float w[n];                              // lane-uniform -> scalar loads
#pragma unroll
  for (int i = 0; i < n; ++i) w[i] = bw[off + i];
  const float l00 = lw[L*4+0], l01 = lw[L*4+1], l10 = lw[L*4+2], l11 = lw[L*4+3];
#pragma unroll
  for (int r = 0; r < 16; ++r) {
    if ((r & h) == 0) {
      const int q = r ^ h;
      const float t0 = w[r & (n-1)] * v[r];
      const float t1 = w[q & (n-1)] * v[q];
      const float y0 = l00*t0 + l10*t1;   // role 0 (exact r11 ordering)
      const float y1 = l01*t0 + l11*t1;   // role 1
      v[r] = RESL ? xr[r] + y0 : y0;
      v[q] = RESL ? xr[q] + y1 : y1;
    }
  }
}

template<int L, bool RESL>
__device__ __forceinline__ void level_dpp(float (&v)[16], const float (&xr)[16],
                                          const float (&w)[16],
                                          const float* __restrict__ lw, int lane) {
  static_assert(L == 4 || L == 5, "DPP levels only");
  constexpr int ctl = (L == 5) ? 0xB1 : 0x4E;
  const int role = (lane >> (5 - L)) & 1;
  const float l00 = lw[L*4+0], l01 = lw[L*4+1], l10 = lw[L*4+2], l11 = lw[L*4+3];
  const float cs = role ? l11 : l00;      // coeff on own t
  const float cp = role ? l01 : l10;      // coeff on partner t
#pragma unroll
  for (int r = 0; r < 16; ++r) {
    const float t = w[r] * v[r];
    const float tp = __int_as_float(
        __builtin_amdgcn_update_dpp(0, __float_as_int(t), ctl, 0xF, 0xF, true));
    const float y = cs*t + cp*tp;
    v[r] = RESL ? xr[r] + y : y;
  }
}

template<int L>
__device__ __forceinline__ void loadw_A(float (&w)[16], const float* lds_bw, int lane) {
  constexpr int n = VECLEN >> L;
  constexpr int off = 2048 - (2048 >> L);
  const int f0 = off + ((lane * 16) & (n - 1));
#pragma unroll
  for (int k = 0; k < 4; ++k) {
    const float4 f = *reinterpret_cast<const float4*>(lds_bw + swz(f0 + 4*k));
    w[4*k+0]=f.x; w[4*k+1]=f.y; w[4*k+2]=f.z; w[4*k+3]=f.w;
  }
}

template<int L>
__device__ __forceinline__ void loadw_B(float* w, const float* lds_bw, int lane) {
  constexpr int off = 2048 - (2048 >> L);
  constexpr int nr = (VECLEN >> L) >> 6;   // 16, 8, 4, 2
#pragma unroll
  for (int j = 0; j < nr; ++j)
    w[j] = lds_bw[swz(off + j*64 + lane)];
}

template<int L, bool RESL>
__device__ __forceinline__ void level_B(float (&v)[16], const float (&xr)[16],
                                        const float* w, const float* __restrict__ lw) {
  constexpr int nr = (VECLEN >> L) >> 6;   // 16, 8, 4, 2
  constexpr int hb = nr >> 1;              // 8, 4, 2, 1
  const float l00 = lw[L*4+0], l01 = lw[L*4+1], l10 = lw[L*4+2], l11 = lw[L*4+3];
#pragma unroll
  for (int r = 0; r < 16; ++r) {
    if ((r & hb) == 0) {
      const int q = r ^ hb;
      const float t0 = w[r & (nr-1)] * v[r];
      const float t1 = w[q & (nr-1)] * v[q];
      const float y0 = l00*t0 + l10*t1;
      const float y1 = l01*t0 + l11*t1;
      v[r] = RESL ? xr[r] + y0 : y0;
      v[q] = RESL ? xr[q] + y1 : y1;
    }
  }
}

__global__ __launch_bounds__(256)
void rnnfft_kernel(const float* __restrict__ x,
                   const float* __restrict__ bw,
                   const float* __restrict__ lw,
                   float* __restrict__ out, int nvec) {
  __shared__ float lds_bw[2048];           // swizzled bw[0..2016)  (8 KB)
  __shared__ float tbuf[4][1024];          // per-wave transpose buffer (16 KB)
  const int t = threadIdx.x;
  const int w4 = t >> 6;
  const int lane = t & 63;
  const int wid = blockIdx.x * 4 + w4;     // wave id = vector id (grid exact)
  const size_t base = (size_t)wid * VECLEN;
  float* buf = tbuf[w4];

  // x in layout A.
  float v[16], xr[16];
#pragma unroll
  for (int k = 0; k < 4; ++k) {
    const float4 f = *reinterpret_cast<const float4*>(x + base + lane*16 + 4*k);
    xr[4*k+0]=f.x; xr[4*k+1]=f.y; xr[4*k+2]=f.z; xr[4*k+3]=f.w;
  }

  // Stage bw[0..2016) into LDS (swizzled), once per block.
  if (t < 252) {
    const float4 a = *reinterpret_cast<const float4*>(bw + 8*t);
    const float4 b = *reinterpret_cast<const float4*>(bw + 8*t + 4);
    *reinterpret_cast<float4*>(lds_bw + swz(8*t)) = a;
    *reinterpret_cast<float4*>(lds_bw + swz(8*t+4)) = b;
  }
  __syncthreads();

#pragma unroll
  for (int r = 0; r < 16; ++r) v[r] = xr[r];

  // Prefetch DPP-level twiddles from LDS (land during in-lane levels).
  float wA[16], wB[16];
  loadw_A<5>(wA, lds_bw, lane);
  loadw_A<4>(wB, lds_bw, lane);

  // Layout A: levels 9..6 in-lane, 5 and 4 via DPP.
  level_inlane<9, true>(v, xr, bw, lw);
  level_inlane<8, true>(v, xr, bw, lw);
  level_inlane<7, true>(v, xr, bw, lw);
  level_inlane<6, true>(v, xr, bw, lw);
  level_dpp<5, true>(v, xr, wA, lw, lane);
  level_dpp<4, true>(v, xr, wB, lw, lane);

  // Transpose v: A -> B (per-wave buffer, in-order DS, no barrier needed).
#pragma unroll
  for (int k = 0; k < 4; ++k) {
    float4 f;
    f.x = v[4*k+0]; f.y = v[4*k+1]; f.z = v[4*k+2]; f.w = v[4*k+3];
    *reinterpret_cast<float4*>(buf + swz(lane*16 + 4*k)) = f;
  }

  // B-layout residual from global — L2/L3 hit now that nt stores keep x
  // resident (same cachelines as the A-layout load). Rides under the DS wait.
  float xrB[16];
#pragma unroll
  for (int r = 0; r < 16; ++r) xrB[r] = x[base + r*64 + lane];

  // B-twiddles for the first two B-levels ride the same DS queue.
  float w3[2], w2[4], w1[8], w0[16];
  loadw_B<3>(w3, lds_bw, lane);
  loadw_B<2>(w2, lds_bw, lane);

#pragma unroll
  for (int r = 0; r < 16; ++r) v[r] = buf[swz(r*64 + lane)];

  // Layout B: levels 3..0 all in-lane (pure VALU).
  level_B<3, true >(v, xrB, w3, lw);
  loadw_B<1>(w1, lds_bw, lane);
  level_B<2, true >(v, xrB, w2, lw);
  loadw_B<0>(w0, lds_bw, lane);
  level_B<1, false>(v, xrB, w1, lw);   // RES[1] = False
  level_B<0, true >(v, xrB, w0, lw);

  // Nontemporal coalesced stores: out never re-read — stream past L2/L3 so
  // write-allocation stops evicting x from Infinity Cache (r22: real win).
#pragma unroll
  for (int r = 0; r < 16; ++r)
    __builtin_nontemporal_store(v[r], &out[base + r*64 + lane]);
}

extern "C" void kernel_launch(void* const* d_in, const int* in_sizes, int n_in,
                              void* d_out, int out_size, void* d_ws, size_t ws_size,
                              hipStream_t stream) {
  const float* x  = (const float*)d_in[0];
  const float* bw = (const float*)d_in[1];
  const float* lw = (const float*)d_in[2];
  float* out = (float*)d_out;
  const int nvec = in_sizes[0] / VECLEN;        // 16384 vectors
  const int wpb = 4;                            // waves per block (256 threads)
  const int blocks = (nvec + wpb - 1) / wpb;    // 4096, exact
  rnnfft_kernel<<<blocks, 256, 0, stream>>>(x, bw, lw, out, nvec);
}

// Round 24
// 29.475 us; speedup vs baseline: 1.0929x; 1.0929x over previous
//
#include <hip/hip_runtime.h>

// RNNFFT: depth-10 radix-2 butterfly network over last dim (1024).
// v = x; for l = 9..0: y = B_l(w_l * v); v = (l==1) ? y : x + y
// Pairs at level l: (e, e^h), h = 512>>l. Twiddle: bw[OFF[l] + (e & (n_l-1))].
// Mix (lw^T): role-j: y = lw[j][j]*t_self + lw[1-j][j]*t_partner.
//
// Structure = r22 (best, 30.5us) with ONE shared per-wave A->B buffer:
//   Layout A (e=lane*16+r): levels 9..6 in-lane; 5,4 via DPP quad_perm.
//   bw staged in LDS (swizzled). nt stores (r22 win: out stops evicting x).
//   xr AND v both transit A->B through the SAME 4KB per-wave buffer -
//   lifetimes are sequential under in-order per-wave DS:
//     write xr -> barrier/phase A -> read xrB -> write v -> read vB.
//   LDS 40 -> 24KB: 6 blocks/CU (r23 tried 24KB via global re-read and lost
//   1.7us to the late L2 round trip; this keeps the LDS passthrough).
//   Layout B (e=r*64+lane): levels 3..0 in-lane; nt coalesced B stores.
// Ledger: occupancy-alone null (r4,r19,r23), VALU null (r14), latency null
// (r15), DS-count reg-blocked (r18), VMEM null (r20), nt stores ~+1us (r22).
// Per-element arithmetic identical to r11 (absmax 7.450581e-9).

constexpr int VECLEN = 1024;

__device__ __forceinline__ int swz(int f) {      // XOR bits[4:2] with bits[7:5]
  return f ^ (((f >> 5) & 7) << 2);              // preserves 16B groups
}

template<int L, bool RESL>
__device__ __forceinline__ void level_inlane(float (&v)[16], const float (&xr)[16],
                                             const float* __restrict__ bw,
                                             const float* __restrict__ lw) {
  constexpr int n = VECLEN >> L;          // 16, 8, 4, 2
  constexpr int h = n >> 1;               // 8, 4, 2, 1
  constexpr int off = 2048 - (2048 >> L); // OFFSETS[L]
  float w[n];                              // lane-uniform -> scalar loads
#pragma unroll
  for (int i = 0; i < n; ++i) w[i] = bw[off + i];
  const float l00 = lw[L*4+0], l01 = lw[L*4+1], l10 = lw[L*4+2], l11 = lw[L*4+3];
#pragma unroll
  for (int r = 0; r < 16; ++r) {
    if ((r & h) == 0) {
      const int q = r ^ h;
      const float t0 = w[r & (n-1)] * v[r];
      const float t1 = w[q & (n-1)] * v[q];
      const float y0 = l00*t0 + l10*t1;   // role 0 (exact r11 ordering)
      const float y1 = l01*t0 + l11*t1;   // role 1
      v[r] = RESL ? xr[r] + y0 : y0;
      v[q] = RESL ? xr[q] + y1 : y1;
    }
  }
}

template<int L, bool RESL>
__device__ __forceinline__ void level_dpp(float (&v)[16], const float (&xr)[16],
                                          const float (&w)[16],
                                          const float* __restrict__ lw, int lane) {
  static_assert(L == 4 || L == 5, "DPP levels only");
  constexpr int ctl = (L == 5) ? 0xB1 : 0x4E;
  const int role = (lane >> (5 - L)) & 1;
  const float l00 = lw[L*4+0], l01 = lw[L*4+1], l10 = lw[L*4+2], l11 = lw[L*4+3];
  const float cs = role ? l11 : l00;      // coeff on own t
  const float cp = role ? l01 : l10;      // coeff on partner t
#pragma unroll
  for (int r = 0; r < 16; ++r) {
    const float t = w[r] * v[r];
    const float tp = __int_as_float(
        __builtin_amdgcn_update_dpp(0, __float_as_int(t), ctl, 0xF, 0xF, true));
    const float y = cs*t + cp*tp;
    v[r] = RESL ? xr[r] + y : y;
  }
}

template<int L>
__device__ __forceinline__ void loadw_A(float (&w)[16], const float* lds_bw, int lane) {
  constexpr int n = VECLEN >> L;
  constexpr int off = 2048 - (2048 >> L);
  const int f0 = off + ((lane * 16) & (n - 1));
#pragma unroll
  for (int k = 0; k < 4; ++k) {
    const float4 f = *reinterpret_cast<const float4*>(lds_bw + swz(f0 + 4*k));
    w[4*k+0]=f.x; w[4*k+1]=f.y; w[4*k+2]=f.z; w[4*k+3]=f.w;
  }
}

template<int L>
__device__ __forceinline__ void loadw_B(float* w, const float* lds_bw, int lane) {
  constexpr int off = 2048 - (2048 >> L);
  constexpr int nr = (VECLEN >> L) >> 6;   // 16, 8, 4, 2
#pragma unroll
  for (int j = 0; j < nr; ++j)
    w[j] = lds_bw[swz(off + j*64 + lane)];
}

template<int L, bool RESL>
__device__ __forceinline__ void level_B(float (&v)[16], const float (&xr)[16],
                                        const float* w, const float* __restrict__ lw) {
  constexpr int nr = (VECLEN >> L) >> 6;   // 16, 8, 4, 2
  constexpr int hb = nr >> 1;              // 8, 4, 2, 1
  const float l00 = lw[L*4+0], l01 = lw[L*4+1], l10 = lw[L*4+2], l11 = lw[L*4+3];
#pragma unroll
  for (int r = 0; r < 16; ++r) {
    if ((r & hb) == 0) {
      const int q = r ^ hb;
      const float t0 = w[r & (nr-1)] * v[r];
      const float t1 = w[q & (nr-1)] * v[q];
      const float y0 = l00*t0 + l10*t1;
      const float y1 = l01*t0 + l11*t1;
      v[r] = RESL ? xr[r] + y0 : y0;
      v[q] = RESL ? xr[q] + y1 : y1;
    }
  }
}

__global__ __launch_bounds__(256)
void rnnfft_kernel(const float* __restrict__ x,
                   const float* __restrict__ bw,
                   const float* __restrict__ lw,
                   float* __restrict__ out, int nvec) {
  __shared__ float lds_bw[2048];           // swizzled bw[0..2016)  (8 KB)
  __shared__ float tbuf[4][1024];          // per-wave SHARED xr/v buffer (16 KB)
  const int t = threadIdx.x;
  const int w4 = t >> 6;
  const int lane = t & 63;
  const int wid = blockIdx.x * 4 + w4;     // wave id = vector id (grid exact)
  const size_t base = (size_t)wid * VECLEN;
  float* buf = tbuf[w4];

  // x in layout A (the ONLY global read of x).
  float v[16], xr[16];
#pragma unroll
  for (int k = 0; k < 4; ++k) {
    const float4 f = *reinterpret_cast<const float4*>(x + base + lane*16 + 4*k);
    xr[4*k+0]=f.x; xr[4*k+1]=f.y; xr[4*k+2]=f.z; xr[4*k+3]=f.w;
  }

  // Stash xr into the shared per-wave buffer (first use of the buffer).
#pragma unroll
  for (int k = 0; k < 4; ++k) {
    float4 f;
    f.x = xr[4*k+0]; f.y = xr[4*k+1]; f.z = xr[4*k+2]; f.w = xr[4*k+3];
    *reinterpret_cast<float4*>(buf + swz(lane*16 + 4*k)) = f;
  }

  // Stage bw[0..2016) into LDS (swizzled), once per block.
  if (t < 252) {
    const float4 a = *reinterpret_cast<const float4*>(bw + 8*t);
    const float4 b = *reinterpret_cast<const float4*>(bw + 8*t + 4);
    *reinterpret_cast<float4*>(lds_bw + swz(8*t)) = a;
    *reinterpret_cast<float4*>(lds_bw + swz(8*t+4)) = b;
  }
  __syncthreads();

#pragma unroll
  for (int r = 0; r < 16; ++r) v[r] = xr[r];

  // Prefetch DPP-level twiddles from LDS (land during in-lane levels).
  float wA[16], wB[16];
  loadw_A<5>(wA, lds_bw, lane);
  loadw_A<4>(wB, lds_bw, lane);

  // Layout A: levels 9..6 in-lane, 5 and 4 via DPP.
  level_inlane<9, true>(v, xr, bw, lw);
  level_inlane<8, true>(v, xr, bw, lw);
  level_inlane<7, true>(v, xr, bw, lw);
  level_inlane<6, true>(v, xr, bw, lw);
  level_dpp<5, true>(v, xr, wA, lw, lane);
  level_dpp<4, true>(v, xr, wB, lw, lane);

  // Read xr back in B layout BEFORE overwriting the buffer with v.
  // In-order per-wave DS: these reads complete (lgkmcnt) before the v-writes
  // below execute - one buffer serves both passthroughs.
  float xrB[16];
#pragma unroll
  for (int r = 0; r < 16; ++r) xrB[r] = buf[swz(r*64 + lane)];

  // Transpose v: A -> B through the same buffer.
#pragma unroll
  for (int k = 0; k < 4; ++k) {
    float4 f;
    f.x = v[4*k+0]; f.y = v[4*k+1]; f.z = v[4*k+2]; f.w = v[4*k+3];
    *reinterpret_cast<float4*>(buf + swz(lane*16 + 4*k)) = f;
  }

  // B-twiddles for the first two B-levels ride the same DS queue.
  float w3[2], w2[4], w1[8], w0[16];
  loadw_B<3>(w3, lds_bw, lane);
  loadw_B<2>(w2, lds_bw, lane);

#pragma unroll
  for (int r = 0; r < 16; ++r) v[r] = buf[swz(r*64 + lane)];

  // Layout B: levels 3..0 all in-lane (pure VALU).
  level_B<3, true >(v, xrB, w3, lw);
  loadw_B<1>(w1, lds_bw, lane);
  level_B<2, true >(v, xrB, w2, lw);
  loadw_B<0>(w0, lds_bw, lane);
  level_B<1, false>(v, xrB, w1, lw);   // RES[1] = False
  level_B<0, true >(v, xrB, w0, lw);

  // Nontemporal coalesced stores: out never re-read — stream past L2/L3 so
  // write-allocation stops evicting x from Infinity Cache (r22: real win).
#pragma unroll
  for (int r = 0; r < 16; ++r)
    __builtin_nontemporal_store(v[r], &out[base + r*64 + lane]);
}

extern "C" void kernel_launch(void* const* d_in, const int* in_sizes, int n_in,
                              void* d_out, int out_size, void* d_ws, size_t ws_size,
                              hipStream_t stream) {
  const float* x  = (const float*)d_in[0];
  const float* bw = (const float*)d_in[1];
  const float* lw = (const float*)d_in[2];
  float* out = (float*)d_out;
  const int nvec = in_sizes[0] / VECLEN;        // 16384 vectors
  const int wpb = 4;                            // waves per block (256 threads)
  const int blocks = (nvec + wpb - 1) / wpb;    // 4096, exact
  rnnfft_kernel<<<blocks, 256, 0, stream>>>(x, bw, lw, out, nvec);
}